// Round 22
// baseline (43.834 us; speedup 1.0000x reference)
//
#include <hip/hip_runtime.h>
#include <hip/hip_bf16.h>

// VQ-VAE vector quantizer, MI355X — single-dispatch champion (self-staging).
// [memset]  4B: loss = 0
// [k_all]   256 blocks x 512thr (1/CU, 8 waves): block owns 128 hw rows of one b.
//   - lat HBM loads issued FIRST (latency hides under staging)
//   - stage emb fp32 -> swizzled fp8 E (x512) + cn IN-KERNEL: 4 thr/row,
//     coalesced 128B quarter-rows, 2 shfl_xor/row (R16's 128-shfl mistake fixed),
//     straight-line cvt_pk, ds_write_b128. No k_prep dispatch, no drain.
//   - A-frags in regs (cvt fp8); row-norms in the same pass
//   - phase B (R13 verbatim): wave owns 16 rows, sweeps 1024 codes from LDS,
//     8 independent acc chains; fp32 fold s = cn - (2/512)*t
//   - in-wave butterfly, gather q=emb[k*] fp32 -> [B,D,H,W], 1 loss atomic/block
// Loss identity: sum||q-x||^2 = sum(min-score) + sum(x^2)  (exact in fp32).

typedef __attribute__((ext_vector_type(4))) float f32x4;

#define LOSS_SCALE (1.25f / 4194304.0f)
#define NEG2_INV_LAMBDA (-2.0f / 512.0f)

static __device__ inline unsigned cvt4_fp8(float a, float b, float c, float d) {
    int v = __builtin_amdgcn_cvt_pk_fp8_f32(a, b, 0, false);
    v = __builtin_amdgcn_cvt_pk_fp8_f32(c, d, v, true);
    return (unsigned)v;
}

// LDS: E @0 (128K, swz) | C @131072 (4K) | win @135168 (512) | rs @135680 (32)
//      = 135712 B, 1 block/CU.
__global__ __launch_bounds__(512, 1) void k_all(const float* __restrict__ lat,
                                                const float* __restrict__ emb,
                                                float* __restrict__ outq,
                                                float* __restrict__ loss) {
    __shared__ __align__(16) char lds[135712];
    char*  ldsE = lds;                       // fp8 swz [1024][128]
    float* ldsC = (float*)(lds + 131072);    // [1024]
    int*   win  = (int*)  (lds + 135168);    // [128]
    float* rs   = (float*)(lds + 135680);    // [8]

    const int t = threadIdx.x, bm = blockIdx.x;     // 256 blocks
    const int lane = t & 63, w = t >> 6;            // 8 waves
    const int l15 = lane & 15, lg = lane >> 4;
    const int b = bm >> 3, hw0 = (bm & 7) << 7;     // 128 rows

    // ---- lat HBM loads FIRST (longest latency; overlaps staging below) ----
    const float* lp = lat + ((size_t)b << 17) + hw0 + (w << 4) + l15;
    float xv[4][8];
#pragma unroll
    for (int ks = 0; ks < 4; ++ks)
#pragma unroll
        for (int j = 0; j < 8; ++j)
            xv[ks][j] = lp[(size_t)(ks * 32 + lg * 8 + j) << 10];

    // ---- stage emb -> fp8 E + cn: 4 threads/row, 8 passes, coalesced ----
    {
        const int qt = t & 3, rbase = t >> 2;       // quarter, row-in-pass
#pragma unroll
        for (int p = 0; p < 8; ++p) {
            const int row = (p << 7) + rbase;       // 0..1023
            const float4* rp4 = (const float4*)(emb + ((size_t)row << 7) + (qt << 5));
            float4 f[8];
#pragma unroll
            for (int j = 0; j < 8; ++j) f[j] = rp4[j];
            float ps = 0.f;
#pragma unroll
            for (int j = 0; j < 8; ++j)
                ps += f[j].x*f[j].x + f[j].y*f[j].y + f[j].z*f[j].z + f[j].w*f[j].w;
            ps += __shfl_xor(ps, 1);
            ps += __shfl_xor(ps, 2);                // 4-lane group = full row
            if (qt == 0) ldsC[row] = ps;
            unsigned u[8];
#pragma unroll
            for (int j = 0; j < 8; ++j)
                u[j] = cvt4_fp8(512.f*f[j].x, 512.f*f[j].y, 512.f*f[j].z, 512.f*f[j].w);
            uint4 w0 = {u[0], u[1], u[2], u[3]};
            uint4 w1 = {u[4], u[5], u[6], u[7]};
            char* rowb = ldsE + row * 128;
            const int sw = (row & 7) << 4;
            *(uint4*)(rowb + (((qt << 5) +  0) ^ sw)) = w0;
            *(uint4*)(rowb + (((qt << 5) + 16) ^ sw)) = w1;
        }
    }

    // ---- A-frags + row norms ----
    float rn = 0.f;
    long av[4];
#pragma unroll
    for (int ks = 0; ks < 4; ++ks) {
#pragma unroll
        for (int j = 0; j < 8; ++j) rn = fmaf(xv[ks][j], xv[ks][j], rn);
        unsigned lo = cvt4_fp8(xv[ks][0], xv[ks][1], xv[ks][2], xv[ks][3]);
        unsigned hi = cvt4_fp8(xv[ks][4], xv[ks][5], xv[ks][6], xv[ks][7]);
        av[ks] = (long)(((unsigned long long)hi << 32) | lo);
    }
    __syncthreads();                 // E + cn resident

    // ---- phase B: barrier-free sweep of all 1024 codes from LDS ----
    float run_s[4]; int run_i[4];
#pragma unroll
    for (int r = 0; r < 4; ++r) { run_s[r] = 3.0e38f; run_i[r] = 0; }

    for (int ct = 0; ct < 8; ++ct) {
        float cnv[8];
#pragma unroll
        for (int c = 0; c < 8; ++c) cnv[c] = ldsC[(ct << 7) + (c << 4) + l15];

        f32x4 acc[8];
#pragma unroll
        for (int c = 0; c < 8; ++c) acc[c] = (f32x4){0.f, 0.f, 0.f, 0.f};
#pragma unroll
        for (int ks = 0; ks < 4; ++ks) {
            long bv[8];
#pragma unroll
            for (int c = 0; c < 8; ++c) {
                int rr = (ct << 7) + (c << 4) + l15;
                bv[c] = *(const long*)(ldsE + rr * 128 +
                         ((ks * 32 + lg * 8) ^ ((rr & 7) << 4)));
            }
#pragma unroll
            for (int c = 0; c < 8; ++c)
                acc[c] = __builtin_amdgcn_mfma_f32_16x16x32_fp8_fp8(av[ks], bv[c], acc[c], 0, 0, 0);
        }
#pragma unroll
        for (int c = 0; c < 8; ++c) {
            int kg = (ct << 7) + (c << 4) + l15;
#pragma unroll
            for (int r = 0; r < 4; ++r) {
                float s = fmaf(NEG2_INV_LAMBDA, acc[c][r], cnv[c]);
                if (s < run_s[r]) { run_s[r] = s; run_i[r] = kg; }
            }
        }
    }

    // ---- in-wave merge: butterfly over 16 cols; win + loss partials ----
    float bs = 0.f;
#pragma unroll
    for (int r = 0; r < 4; ++r) {
        float s = run_s[r]; int bi = run_i[r];
#pragma unroll
        for (int mask = 1; mask < 16; mask <<= 1) {
            float os = __shfl_xor(s, mask);
            int   oi = __shfl_xor(bi, mask);
            if (os < s || (os == s && oi < bi)) { s = os; bi = oi; }
        }
        if (l15 == 0) {
            win[(w << 4) + (lg << 2) + r] = bi;    // C row = lg*4 + reg
            bs += s;
        }
    }
    {
        float v = ((l15 == 0) ? bs : 0.f) + rn;
#pragma unroll
        for (int m = 1; m < 64; m <<= 1) v += __shfl_xor(v, m);
        if (lane == 0) rs[w] = v;
    }
    __syncthreads();
    if (t == 0) {
        float v = rs[0] + rs[1] + rs[2] + rs[3] + rs[4] + rs[5] + rs[6] + rs[7];
        atomicAdd(loss, v * LOSS_SCALE);
    }

    // ---- gather q = emb[k*] fp32, store [B,D,H,W] coalesced ----
    {
        const int rowl = t & 127, dg = t >> 7;      // 4 dgrps x 32 d
        const int bi = win[rowl];
        const float4* eg = (const float4*)(emb + ((size_t)bi << 7) + (dg << 5));
        float* ob = outq + ((size_t)b << 17) + ((size_t)(dg << 5) << 10) + hw0 + rowl;
#pragma unroll
        for (int jj = 0; jj < 8; ++jj) {
            float4 v = eg[jj];
            ob[(size_t)(jj * 4 + 0) << 10] = v.x;
            ob[(size_t)(jj * 4 + 1) << 10] = v.y;
            ob[(size_t)(jj * 4 + 2) << 10] = v.z;
            ob[(size_t)(jj * 4 + 3) << 10] = v.w;
        }
    }
}

extern "C" void kernel_launch(void* const* d_in, const int* in_sizes, int n_in,
                              void* d_out, int out_size, void* d_ws, size_t ws_size,
                              hipStream_t stream) {
    const float* lat = (const float*)d_in[0];   // [32,128,32,32]
    const float* emb = (const float*)d_in[1];   // [1024,128]
    float* out = (float*)d_out;                 // q (4194304) + vq_loss (1)
    float* loss = out + 4194304;

    hipMemsetAsync(loss, 0, 4, stream);         // zero the loss accumulator
    k_all<<<256, 512, 0, stream>>>(lat, emb, out, loss);
}

// Round 23
// 30.507 us; speedup vs baseline: 1.4368x; 1.4368x over previous
//
#include <hip/hip_runtime.h>
#include <hip/hip_bf16.h>

// VQ-VAE vector quantizer, MI355X — FINAL champion (E-resident single-pass).
// Best measured: 30.65 us (reproduced 3x: 30.65/30.69/30.76), absmax 1.95e-3
// (threshold 2.5e-2). Search locked after 22 rounds; see round journal.
// [k_prep]  64 blocks: emb -> swizzled fp8 E (x512) + cn=||e||^2 fp32; loss=0
// [k_fused] 256 blocks x 512thr (1/CU, 8 waves): block owns 128 hw rows of one b.
//   - stage ENTIRE fp8 E image (128KB) into LDS once (global_load_lds w16),
//     chunk order rotated by (blockIdx & 15)
//   - A-frags direct from lat (regs, cvt fp8); row-norms in the same pass
//   - phase B barrier-free: wave owns 16 rows, sweeps 1024 codes from LDS,
//     8 independent acc chains; fp32 fold s = cn - (2/512)*t
//   - in-wave butterfly, gather q=emb[k*] fp32 -> [B,D,H,W], 1 loss atomic/block
// Loss identity: sum||q-x||^2 = sum(min-score) + sum(x^2)  (exact in fp32).

typedef __attribute__((ext_vector_type(4))) float f32x4;

// workspace layout (bytes)
#define WS_E 0u          // fp8 swz [1024][128] = 131072
#define WS_C 131072u     // f32 cn[1024]        = 4096

#define LOSS_SCALE (1.25f / 4194304.0f)
#define NEG2_INV_LAMBDA (-2.0f / 512.0f)

static __device__ inline unsigned cvt4_fp8(float a, float b, float c, float d) {
    int v = __builtin_amdgcn_cvt_pk_fp8_f32(a, b, 0, false);
    v = __builtin_amdgcn_cvt_pk_fp8_f32(c, d, v, true);
    return (unsigned)v;
}

static __device__ inline void gload_lds16(const void* g, void* l) {
    __builtin_amdgcn_global_load_lds(
        (const __attribute__((address_space(1))) unsigned int*)g,
        (__attribute__((address_space(3))) unsigned int*)l, 16, 0, 0);
}

// ---------------- codebook prep ----------------
__global__ __launch_bounds__(256) void k_prep(const float* __restrict__ emb,
                                              char* __restrict__ Eb,
                                              float* __restrict__ cn,
                                              float* __restrict__ loss) {
    const int t = threadIdx.x;
    const int row = (blockIdx.x << 4) + (t >> 4), c = t & 15;
    const float4* ep = (const float4*)(emb + ((size_t)row << 7) + (c << 3));
    float4 e0 = ep[0], e1 = ep[1];
    float s = e0.x*e0.x + e0.y*e0.y + e0.z*e0.z + e0.w*e0.w
            + e1.x*e1.x + e1.y*e1.y + e1.z*e1.z + e1.w*e1.w;
#pragma unroll
    for (int m = 1; m < 16; m <<= 1) s += __shfl_xor(s, m);
    if (c == 0) cn[row] = s;
    uint2 v;
    v.x = cvt4_fp8(512.f*e0.x, 512.f*e0.y, 512.f*e0.z, 512.f*e0.w);
    v.y = cvt4_fp8(512.f*e1.x, 512.f*e1.y, 512.f*e1.z, 512.f*e1.w);
    *(uint2*)(Eb + row * 128 + ((c * 8) ^ ((row & 7) << 4))) = v;
    if (blockIdx.x == 0 && t == 0) loss[0] = 0.f;
}

// ---------------- fused: E-resident scoring + gather ----------------
// LDS: E @0 (128K) | win @131072 (512B) | rs @131584 (32B) = 131616 B.
__global__ __launch_bounds__(512, 1) void k_fused(const float* __restrict__ lat,
                                                  const float* __restrict__ emb,
                                                  const char* __restrict__ Eb,
                                                  const float* __restrict__ cn,
                                                  float* __restrict__ outq,
                                                  float* __restrict__ loss) {
    __shared__ char lds[131616];
    char*  ldsE = lds;                       // fp8 swz [1024][128]
    int*   win  = (int*)  (lds + 131072);    // [128]
    float* rs   = (float*)(lds + 131584);    // [8]

    const int t = threadIdx.x, bm = blockIdx.x;     // 256 blocks
    const int lane = t & 63, w = t >> 6;            // 8 waves
    const int l15 = lane & 15, lg = lane >> 4;
    const int b = bm >> 3, hw0 = (bm & 7) << 7;     // 128 rows, line-aligned
    const int rot = bm & 15;                        // stagger phase

    // ---- stage full E image (128 KB), chunk order rotated per block ----
#pragma unroll
    for (int i = 0; i < 16; ++i) {
        int chunk = (i + rot) & 15;                 // 16 chunks of 8 KB
        int base = chunk * 8192 + (w << 10);        // wave-uniform byte base
        gload_lds16(Eb + base + lane * 16, ldsE + base);
    }

    // ---- A-frags direct from lat (regs), row-norm partial in same pass ----
    const float* lp = lat + ((size_t)b << 17) + hw0 + (w << 4) + l15;
    float xv[4][8];
#pragma unroll
    for (int ks = 0; ks < 4; ++ks)
#pragma unroll
        for (int j = 0; j < 8; ++j)
            xv[ks][j] = lp[(size_t)(ks * 32 + lg * 8 + j) << 10];

    float rn = 0.f;
    long av[4];
#pragma unroll
    for (int ks = 0; ks < 4; ++ks) {
#pragma unroll
        for (int j = 0; j < 8; ++j) rn = fmaf(xv[ks][j], xv[ks][j], rn);
        unsigned lo = cvt4_fp8(xv[ks][0], xv[ks][1], xv[ks][2], xv[ks][3]);
        unsigned hi = cvt4_fp8(xv[ks][4], xv[ks][5], xv[ks][6], xv[ks][7]);
        av[ks] = (long)(((unsigned long long)hi << 32) | lo);
    }
    __syncthreads();                 // E image resident (vmcnt drained)

    // ---- phase B: barrier-free sweep of all 1024 codes from LDS ----
    float run_s[4]; int run_i[4];
#pragma unroll
    for (int r = 0; r < 4; ++r) { run_s[r] = 3.0e38f; run_i[r] = 0; }

    for (int ct = 0; ct < 8; ++ct) {
        float cnv[8];
#pragma unroll
        for (int c = 0; c < 8; ++c) cnv[c] = cn[(ct << 7) + (c << 4) + l15];

        f32x4 acc[8];
#pragma unroll
        for (int c = 0; c < 8; ++c) acc[c] = (f32x4){0.f, 0.f, 0.f, 0.f};
#pragma unroll
        for (int ks = 0; ks < 4; ++ks) {
            long bv[8];
#pragma unroll
            for (int c = 0; c < 8; ++c) {
                int rr = (ct << 7) + (c << 4) + l15;
                bv[c] = *(const long*)(ldsE + rr * 128 +
                         ((ks * 32 + lg * 8) ^ ((rr & 7) << 4)));
            }
#pragma unroll
            for (int c = 0; c < 8; ++c)
                acc[c] = __builtin_amdgcn_mfma_f32_16x16x32_fp8_fp8(av[ks], bv[c], acc[c], 0, 0, 0);
        }
#pragma unroll
        for (int c = 0; c < 8; ++c) {
            int kg = (ct << 7) + (c << 4) + l15;
#pragma unroll
            for (int r = 0; r < 4; ++r) {
                float s = fmaf(NEG2_INV_LAMBDA, acc[c][r], cnv[c]);
                if (s < run_s[r]) { run_s[r] = s; run_i[r] = kg; }
            }
        }
    }

    // ---- in-wave merge: butterfly over 16 cols; win + loss partials ----
    float bs = 0.f;
#pragma unroll
    for (int r = 0; r < 4; ++r) {
        float s = run_s[r]; int bi = run_i[r];
#pragma unroll
        for (int mask = 1; mask < 16; mask <<= 1) {
            float os = __shfl_xor(s, mask);
            int   oi = __shfl_xor(bi, mask);
            if (os < s || (os == s && oi < bi)) { s = os; bi = oi; }
        }
        if (l15 == 0) {
            win[(w << 4) + (lg << 2) + r] = bi;    // C row = lg*4 + reg
            bs += s;
        }
    }
    {
        float v = ((l15 == 0) ? bs : 0.f) + rn;
#pragma unroll
        for (int m = 1; m < 64; m <<= 1) v += __shfl_xor(v, m);
        if (lane == 0) rs[w] = v;
    }
    __syncthreads();
    if (t == 0) {
        float v = rs[0] + rs[1] + rs[2] + rs[3] + rs[4] + rs[5] + rs[6] + rs[7];
        atomicAdd(loss, v * LOSS_SCALE);
    }

    // ---- gather q = emb[k*] fp32, store [B,D,H,W] coalesced ----
    {
        const int rowl = t & 127, dg = t >> 7;      // 4 dgrps x 32 d
        const int bi = win[rowl];
        const float4* eg = (const float4*)(emb + ((size_t)bi << 7) + (dg << 5));
        float* ob = outq + ((size_t)b << 17) + ((size_t)(dg << 5) << 10) + hw0 + rowl;
#pragma unroll
        for (int jj = 0; jj < 8; ++jj) {
            float4 v = eg[jj];
            ob[(size_t)(jj * 4 + 0) << 10] = v.x;
            ob[(size_t)(jj * 4 + 1) << 10] = v.y;
            ob[(size_t)(jj * 4 + 2) << 10] = v.z;
            ob[(size_t)(jj * 4 + 3) << 10] = v.w;
        }
    }
}

extern "C" void kernel_launch(void* const* d_in, const int* in_sizes, int n_in,
                              void* d_out, int out_size, void* d_ws, size_t ws_size,
                              hipStream_t stream) {
    const float* lat = (const float*)d_in[0];   // [32,128,32,32]
    const float* emb = (const float*)d_in[1];   // [1024,128]
    float* out = (float*)d_out;                 // q (4194304) + vq_loss (1)
    char* ws = (char*)d_ws;
    char*  E    = ws + WS_E;
    float* cn   = (float*)(ws + WS_C);
    float* loss = out + 4194304;

    k_prep <<<64,  256, 0, stream>>>(emb, E, cn, loss);
    k_fused<<<256, 512, 0, stream>>>(lat, emb, E, cn, out, loss);
}